// Round 4
// baseline (683.382 us; speedup 1.0000x reference)
//
#include <hip/hip_runtime.h>
#include <hip/hip_bf16.h>
#include <cstdint>

#define Bsz   4
#define Ssz   512
#define HIDsz 4096
#define NHsz  32
#define NKVsz 8
#define Dsz   128
#define CAPsz 2048
#define EPSf  1e-6f
#define QK_SCALEf 0.08838834764831845f  // 1/sqrt(128)

typedef __attribute__((ext_vector_type(8))) short short8;
typedef __attribute__((ext_vector_type(4))) float f32x4;

__device__ __forceinline__ unsigned short f2bf(float x) {
    unsigned u = __float_as_uint(x);
    return (unsigned short)((u + 0x7fffu + ((u >> 16) & 1u)) >> 16);
}

// async 16B global->LDS; lds base must be WAVE-UNIFORM (HW adds lane*16)
__device__ __forceinline__ void gload16(const void* g, void* l) {
    __builtin_amdgcn_global_load_lds(
        (const __attribute__((address_space(1))) unsigned int*)g,
        (__attribute__((address_space(3))) unsigned int*)l, 16, 0, 0);
}

// ============================================================================
// f32 -> bf16 flat convert (vectorized float4 -> ushort4)
// ============================================================================
__global__ __launch_bounds__(256) void convert_bf16_kernel(
    const float* __restrict__ in, unsigned short* __restrict__ out, int n4)
{
    int i = blockIdx.x * blockDim.x + threadIdx.x;
    if (i < n4) {
        float4 v = ((const float4*)in)[i];
        ushort4 o;
        o.x = f2bf(v.x); o.y = f2bf(v.y); o.z = f2bf(v.z); o.w = f2bf(v.w);
        ((ushort4*)out)[i] = o;
    }
}

// ============================================================================
// R4: K cache f32 -> bf16, but only rows pos < start (prefix). Rows
// [start, start+S) are written bf16 by rmsnorm_rope; rows >= start+S are
// never read by attn (t_hi <= start+s0+15 < start+S).
// ============================================================================
__global__ __launch_bounds__(256) void convert_k_prefix_kernel(
    const float* __restrict__ in, unsigned short* __restrict__ out,
    const int* __restrict__ start_idx)
{
    int i = blockIdx.x * blockDim.x + threadIdx.x;   // one float4 group
    int pos = (i >> 5) & (CAPsz - 1);                // 32 groups per 128-d row
    int b   = i >> 19;                               // 2^19 groups per batch
    if (pos >= start_idx[b]) return;
    float4 v = ((const float4*)in)[i];
    ushort4 o;
    o.x = f2bf(v.x); o.y = f2bf(v.y); o.z = f2bf(v.z); o.w = f2bf(v.w);
    ((ushort4*)out)[i] = o;
}

// ============================================================================
// W (K x N, f32 row-major) -> Wt (N x K, bf16 row-major). 64x64 tiles.
// (still used for Wo)
// ============================================================================
__global__ __launch_bounds__(256) void transpose_bf16_kernel(
    const float* __restrict__ W, unsigned short* __restrict__ Wt, int K, int N)
{
    __shared__ float tile[64][65];
    const int k0 = blockIdx.y * 64, n0 = blockIdx.x * 64;
    const int t = threadIdx.x;
    const int tr = t >> 4, tc4 = (t & 15) * 4;
#pragma unroll
    for (int i = 0; i < 4; i++) {
        int r = tr + i * 16;
        float4 v = *(const float4*)(W + (size_t)(k0 + r) * N + n0 + tc4);
        tile[r][tc4 + 0] = v.x; tile[r][tc4 + 1] = v.y;
        tile[r][tc4 + 2] = v.z; tile[r][tc4 + 3] = v.w;
    }
    __syncthreads();
#pragma unroll
    for (int i = 0; i < 4; i++) {
        int nr = tr + i * 16;
        ushort4 o;
        o.x = f2bf(tile[tc4 + 0][nr]);
        o.y = f2bf(tile[tc4 + 1][nr]);
        o.z = f2bf(tile[tc4 + 2][nr]);
        o.w = f2bf(tile[tc4 + 3][nr]);
        *(ushort4*)(Wt + (size_t)(n0 + nr) * K + k0 + tc4) = o;
    }
}

// ============================================================================
// R4: fused Wq/Wk/Wv transpose into stacked Wqkv_t (6144 x 4096 bf16).
// blockIdx.x = stacked 64-col tile: [0,64) Q, [64,80) K, [80,96) V.
// ============================================================================
__global__ __launch_bounds__(256) void transpose_wqkv_kernel(
    const float* __restrict__ Wq, const float* __restrict__ Wk,
    const float* __restrict__ Wv, unsigned short* __restrict__ Wt)
{
    __shared__ float tile[64][65];
    const int nt = blockIdx.x;
    const int k0 = blockIdx.y * 64;
    const float* W; int srcN, c0;
    if (nt < 64)      { W = Wq; srcN = 4096; c0 = nt * 64; }
    else if (nt < 80) { W = Wk; srcN = 1024; c0 = (nt - 64) * 64; }
    else              { W = Wv; srcN = 1024; c0 = (nt - 80) * 64; }
    const int t = threadIdx.x;
    const int tr = t >> 4, tc4 = (t & 15) * 4;
#pragma unroll
    for (int i = 0; i < 4; i++) {
        int r = tr + i * 16;
        float4 v = *(const float4*)(W + (size_t)(k0 + r) * srcN + c0 + tc4);
        tile[r][tc4 + 0] = v.x; tile[r][tc4 + 1] = v.y;
        tile[r][tc4 + 2] = v.z; tile[r][tc4 + 3] = v.w;
    }
    __syncthreads();
    const int n0 = nt * 64;   // stacked output row base
#pragma unroll
    for (int i = 0; i < 4; i++) {
        int nr = tr + i * 16;
        ushort4 o;
        o.x = f2bf(tile[tc4 + 0][nr]);
        o.y = f2bf(tile[tc4 + 1][nr]);
        o.z = f2bf(tile[tc4 + 2][nr]);
        o.w = f2bf(tile[tc4 + 3][nr]);
        *(ushort4*)(Wt + (size_t)(n0 + nr) * HIDsz + k0 + tc4) = o;
    }
}

// ============================================================================
// V cache (B,NKV,CAP,D f32) -> Vt (B,NKV,D,CAP bf16). 64x64 tiles per (b,kv).
// R4: skip cap-tiles beyond start+S (attn never reads them).
// ============================================================================
__global__ __launch_bounds__(256) void transpose_v_kernel(
    const float* __restrict__ V, unsigned short* __restrict__ Vt,
    const int* __restrict__ start_idx)
{
    __shared__ float tile[64][65];   // [cap][d]
    const int c0 = blockIdx.x * 64, d0 = blockIdx.y * 64, bk = blockIdx.z;
    if (c0 >= start_idx[bk >> 3] + Ssz) return;
    const int t = threadIdx.x;
    const int tr = t >> 4, tc4 = (t & 15) * 4;
    const float* base = V + (size_t)bk * CAPsz * Dsz;
#pragma unroll
    for (int i = 0; i < 4; i++) {
        int r = tr + i * 16;
        float4 v = *(const float4*)(base + (size_t)(c0 + r) * Dsz + d0 + tc4);
        tile[r][tc4 + 0] = v.x; tile[r][tc4 + 1] = v.y;
        tile[r][tc4 + 2] = v.z; tile[r][tc4 + 3] = v.w;
    }
    __syncthreads();
    unsigned short* ob = Vt + (size_t)bk * Dsz * CAPsz;
#pragma unroll
    for (int i = 0; i < 4; i++) {
        int dr = tr + i * 16;
        ushort4 o;
        o.x = f2bf(tile[tc4 + 0][dr]);
        o.y = f2bf(tile[tc4 + 1][dr]);
        o.z = f2bf(tile[tc4 + 2][dr]);
        o.w = f2bf(tile[tc4 + 3][dr]);
        *(ushort4*)(ob + (size_t)(d0 + dr) * CAPsz + c0 + tc4) = o;
    }
}

// ============================================================================
// bf16 MFMA GEMM (m97 structure): C(MxN,f32) = A(MxK,bf16) @ Bt(NxK,bf16)^T
// Plain row-major f32 write (used for the output projection).
// R4: launch_bounds min-waves 2 -> 3 (residency probe; regs 140 <= 168).
// ============================================================================
__global__ __launch_bounds__(256, 3) void gemm_bf16_kernel(
    const unsigned short* __restrict__ A,   // M x K
    const unsigned short* __restrict__ Bt,  // N x K
    float* __restrict__ C, int M, int N, int K)
{
    __shared__ __align__(16) unsigned short As[128 * 64];
    __shared__ __align__(16) unsigned short Bs[128 * 64];
    const int t    = threadIdx.x;
    const int lane = t & 63, wv = t >> 6;
    const int m0 = blockIdx.y * 128, n0 = blockIdx.x * 128;
    const int rw = (wv & 1) * 64, cw = (wv >> 1) * 64;

    f32x4 acc[4][4];
#pragma unroll
    for (int r = 0; r < 4; r++)
#pragma unroll
        for (int c = 0; c < 4; c++) acc[r][c] = (f32x4){0.f, 0.f, 0.f, 0.f};

    const int arow = lane >> 3;          // 0..7 row within 8-row chunk
    const int acol = (lane & 7) * 8;     // k offset (8 bf16 = 16 B)
    const int fr = lane & 15, fq = (lane >> 4) * 8;

    for (int k0 = 0; k0 < K; k0 += 64) {
        __syncthreads();
#pragma unroll
        for (int i = 0; i < 4; i++) {
            int ro = (i * 4 + wv) * 8;   // 16 chunks x 8 rows = 128 rows
            gload16(A  + (size_t)(m0 + ro + arow) * K + k0 + acol, As + (size_t)ro * 64);
            gload16(Bt + (size_t)(n0 + ro + arow) * K + k0 + acol, Bs + (size_t)ro * 64);
        }
        __syncthreads();
#pragma unroll
        for (int kk = 0; kk < 2; kk++) {
            short8 af[4], bfr[4];
#pragma unroll
            for (int r = 0; r < 4; r++)
                af[r] = *(const short8*)&As[(rw + r * 16 + fr) * 64 + kk * 32 + fq];
#pragma unroll
            for (int c = 0; c < 4; c++)
                bfr[c] = *(const short8*)&Bs[(cw + c * 16 + fr) * 64 + kk * 32 + fq];
#pragma unroll
            for (int r = 0; r < 4; r++)
#pragma unroll
                for (int c = 0; c < 4; c++)
                    acc[r][c] = __builtin_amdgcn_mfma_f32_16x16x32_bf16(
                        af[r], bfr[c], acc[r][c], 0, 0, 0);
        }
    }

#pragma unroll
    for (int r = 0; r < 4; r++) {
#pragma unroll
        for (int c = 0; c < 4; c++) {
            int col = n0 + cw + c * 16 + (lane & 15);
#pragma unroll
            for (int reg = 0; reg < 4; reg++) {
                int row = m0 + rw + r * 16 + (lane >> 4) * 4 + reg;
                C[(size_t)row * N + col] = acc[r][c][reg];
            }
        }
    }
}

// ============================================================================
// FUSED QKV projection GEMM. Bt = [Wq_t; Wk_t; Wv_t] stacked, N = 6144.
// Epilogue routes by n0 (block-uniform). R4: launch_bounds (256,3).
// ============================================================================
__global__ __launch_bounds__(256, 3) void gemm_qkv_kernel(
    const unsigned short* __restrict__ A,    // 2048 x 4096 bf16
    const unsigned short* __restrict__ Bt,   // 6144 x 4096 bf16
    float* __restrict__ Cq,                  // 2048 x 4096 f32
    float* __restrict__ Ck,                  // [B][NKV][CAP][D] f32
    float* __restrict__ Cv,                  // [B][NKV][CAP][D] f32
    const int* __restrict__ start_idx)
{
    __shared__ __align__(16) unsigned short As[128 * 64];
    __shared__ __align__(16) unsigned short Bs[128 * 64];
    const int t    = threadIdx.x;
    const int lane = t & 63, wv = t >> 6;
    const int m0 = blockIdx.y * 128, n0 = blockIdx.x * 128;
    const int rw = (wv & 1) * 64, cw = (wv >> 1) * 64;

    f32x4 acc[4][4];
#pragma unroll
    for (int r = 0; r < 4; r++)
#pragma unroll
        for (int c = 0; c < 4; c++) acc[r][c] = (f32x4){0.f, 0.f, 0.f, 0.f};

    const int arow = lane >> 3;
    const int acol = (lane & 7) * 8;
    const int fr = lane & 15, fq = (lane >> 4) * 8;

    for (int k0 = 0; k0 < HIDsz; k0 += 64) {
        __syncthreads();
#pragma unroll
        for (int i = 0; i < 4; i++) {
            int ro = (i * 4 + wv) * 8;
            gload16(A  + (size_t)(m0 + ro + arow) * HIDsz + k0 + acol, As + (size_t)ro * 64);
            gload16(Bt + (size_t)(n0 + ro + arow) * HIDsz + k0 + acol, Bs + (size_t)ro * 64);
        }
        __syncthreads();
#pragma unroll
        for (int kk = 0; kk < 2; kk++) {
            short8 af[4], bfr[4];
#pragma unroll
            for (int r = 0; r < 4; r++)
                af[r] = *(const short8*)&As[(rw + r * 16 + fr) * 64 + kk * 32 + fq];
#pragma unroll
            for (int c = 0; c < 4; c++)
                bfr[c] = *(const short8*)&Bs[(cw + c * 16 + fr) * 64 + kk * 32 + fq];
#pragma unroll
            for (int r = 0; r < 4; r++)
#pragma unroll
                for (int c = 0; c < 4; c++)
                    acc[r][c] = __builtin_amdgcn_mfma_f32_16x16x32_bf16(
                        af[r], bfr[c], acc[r][c], 0, 0, 0);
        }
    }

    const int pos0 = start_idx[m0 >> 9];
    const bool isQ = (n0 < 4096);
    const bool isK = (n0 >= 4096) && (n0 < 5120);
    float* dst = isK ? Ck : Cv;
    const int cbase = isK ? 4096 : 5120;
#pragma unroll
    for (int r = 0; r < 4; r++) {
#pragma unroll
        for (int c = 0; c < 4; c++) {
            int col = n0 + cw + c * 16 + (lane & 15);
#pragma unroll
            for (int reg = 0; reg < 4; reg++) {
                int row = m0 + rw + r * 16 + (lane >> 4) * 4 + reg;
                float val = acc[r][c][reg];
                if (isQ) {
                    Cq[(size_t)row * 4096 + col] = val;
                } else {
                    int cc = col - cbase;               // 0..1023
                    int pos = pos0 + (row & (Ssz - 1));
                    int b = row >> 9;
                    dst[((size_t)(b * NKVsz + (cc >> 7)) * CAPsz + pos) * Dsz + (cc & 127)] = val;
                }
            }
        }
    }
}

// ============================================================================
// RMSNorm + RoPE, one wave per (token, head) row of 128.
// mode 0: read X f32 (2048, nheads*128), write Xbf bf16 scaled by QK_SCALE
// mode 1: in-place f32 on (B, nheads, CAP, D) cache at row pos=start+s;
//         R4: ALSO writes unscaled bf16 into Xbf at the same offset (Kbf).
// ============================================================================
__global__ __launch_bounds__(256) void rmsnorm_rope_kernel(
    float* __restrict__ X, unsigned short* __restrict__ Xbf,
    const float* __restrict__ w,
    const float* __restrict__ rope, const int* __restrict__ start_idx,
    int nheads, int mode)
{
    int gid   = blockIdx.x * blockDim.x + threadIdx.x;
    int wid   = gid >> 6;
    int lane  = threadIdx.x & 63;
    int token = wid / nheads;
    int h     = wid - token * nheads;
    int b = token >> 9, s = token & (Ssz - 1);
    int pos = start_idx[b] + s;
    size_t off;
    if (mode == 0) off = (size_t)token * (nheads * Dsz) + h * Dsz;
    else           off = ((size_t)(b * nheads + h) * CAPsz + pos) * Dsz;
    float* row = X + off;

    float x1 = row[lane], x2 = row[lane + 64];
    float ss = x1 * x1 + x2 * x2;
#pragma unroll
    for (int off2 = 32; off2 > 0; off2 >>= 1) ss += __shfl_xor(ss, off2);
    float rn  = rsqrtf(ss * (1.f / 128.f) + EPSf);
    float xn1 = x1 * rn * w[lane];
    float xn2 = x2 * rn * w[lane + 64];
    float c   = rope[(size_t)pos * Dsz + lane];        // cos
    float sn  = rope[(size_t)pos * Dsz + 64 + lane];   // sin
    float o1 = xn1 * c - xn2 * sn;
    float o2 = xn2 * c + xn1 * sn;
    if (mode == 0) {
        unsigned short* orow = Xbf + off;
        orow[lane]      = f2bf(o1 * QK_SCALEf);
        orow[lane + 64] = f2bf(o2 * QK_SCALEf);
    } else {
        row[lane]      = o1;
        row[lane + 64] = o2;
        unsigned short* orow = Xbf + off;   // Kbf, same layout
        orow[lane]      = f2bf(o1);
        orow[lane + 64] = f2bf(o2);
    }
}

// ============================================================================
// MFMA flash attention. R4: 16 q-rows per block (was 32) -> grid 1024 blocks,
// LDS 41984 B -> 3 blocks/CU (was 2), finer tail balance. Block = (16 q-rows,
// kv-group, batch), 4 waves = 4 GQA heads sharing one K/V LDS tile.
// K tile [key][d], V^T tile [d][key], both XOR-swizzled (R1). T14 async-STAGE
// (R2): global->reg->LDS, prefetch over compute, raw s_barrier w/o vmcnt
// drain. T5 setprio around MFMA clusters.
// ============================================================================
__global__ __launch_bounds__(256, 3) void attn_mfma_kernel(
    const unsigned short* __restrict__ Qbf,   // [B][S][NH*D]
    const unsigned short* __restrict__ Kbf,   // [B][NKV][CAP][D]
    const unsigned short* __restrict__ Vtbf,  // [B][NKV][D][CAP]
    unsigned short* __restrict__ O,           // [B][S][NH*D]
    const int* __restrict__ start_idx)
{
    __shared__ __align__(16) unsigned short Ks[64 * 128];     // [key][d] swizzled
    __shared__ __align__(16) unsigned short Vs[128 * 64];     // [d][key] swizzled
    __shared__ __align__(16) unsigned short Ps[4][16 * 72];   // per-wave [row][key], pad 72

    const int t = threadIdx.x, lane = t & 63, wv = t >> 6;
    const int l15 = lane & 15, l4 = lane >> 4;
    const int qt = blockIdx.x, kv = blockIdx.y, b = blockIdx.z;
    const int h = kv * 4 + wv;
    const int s0 = qt * 16;
    const int start = start_idx[b];

    // read-side swizzle term: row&7 == l15&7 for all fragment reads
    const int swz = (l15 & 7) << 3;

    // Q a-frags: A[m=l15][k=l4*8+j], 1 m-tile x 4 k-tiles (d=128)
    short8 aq[4];
    const unsigned short* qb = Qbf + ((size_t)(b * Ssz + s0)) * HIDsz + h * Dsz;
#pragma unroll
    for (int kq = 0; kq < 4; kq++)
        aq[kq] = *(const short8*)(qb + (size_t)l15 * HIDsz + kq * 32 + l4 * 8);

    f32x4 Oacc[8];
    float m_run[4], l_run[4];
#pragma unroll
    for (int nd = 0; nd < 8; nd++) Oacc[nd] = (f32x4){0.f, 0.f, 0.f, 0.f};
#pragma unroll
    for (int r = 0; r < 4; r++) { m_run[r] = -1e30f; l_run[r] = 0.f; }

    const unsigned short* kb = Kbf + (size_t)(b * NKVsz + kv) * CAPsz * Dsz;
    const unsigned short* vb = Vtbf + (size_t)(b * NKVsz + kv) * (size_t)Dsz * CAPsz;

    int t_hi = start + s0 + 15;
    if (t_hi > CAPsz - 1) t_hi = CAPsz - 1;

    // staging geometry: K chunk i covers rows (i*4+wv)*4 + l4, 16B slot l15;
    //                   V chunk i covers rows (i*4+wv)*8 + (lane>>3), slot lane&7.
    // LDS write address carries the XOR swizzle; global reads stay linear.
    int krow[4], vrow[4];
    unsigned short* kw[4];
    unsigned short* vw[4];
#pragma unroll
    for (int i = 0; i < 4; i++) {
        int kr = (i * 4 + wv) * 4 + l4;
        krow[i] = kr;
        kw[i] = &Ks[kr * 128 + ((l15 * 8) ^ ((kr & 7) << 3))];
        int vr = (i * 4 + wv) * 8 + (lane >> 3);
        vrow[i] = vr;
        vw[i] = &Vs[vr * 64 + (((lane & 7) * 8) ^ ((vr & 7) << 3))];
    }

    // prologue: tile 0 -> regs
    short8 kreg[4], vreg[4];
#pragma unroll
    for (int i = 0; i < 4; i++) {
        kreg[i] = *(const short8*)(kb + (size_t)krow[i] * Dsz + l15 * 8);
        vreg[i] = *(const short8*)(vb + (size_t)vrow[i] * CAPsz + (lane & 7) * 8);
    }

    for (int t0 = 0; t0 <= t_hi; t0 += 64) {
        // barrier 1: all waves done reading Ks/Vs of previous tile
        asm volatile("s_waitcnt lgkmcnt(0)" ::: "memory");
        __builtin_amdgcn_s_barrier();
        __builtin_amdgcn_sched_barrier(0);

        // write tile t (regs -> LDS, swizzled)
#pragma unroll
        for (int i = 0; i < 4; i++) *(short8*)kw[i] = kreg[i];
#pragma unroll
        for (int i = 0; i < 4; i++) *(short8*)vw[i] = vreg[i];

        // issue tile t+1 global loads (land during compute; no vmcnt at barrier)
        if (t0 + 64 <= t_hi) {
            int tn = t0 + 64;
#pragma unroll
            for (int i = 0; i < 4; i++) {
                kreg[i] = *(const short8*)(kb + (size_t)(tn + krow[i]) * Dsz + l15 * 8);
                vreg[i] = *(const short8*)(vb + (size_t)vrow[i] * CAPsz + tn + (lane & 7) * 8);
            }
        }

        // barrier 2: LDS writes visible to all waves (lgkmcnt only, NOT vmcnt)
        asm volatile("s_waitcnt lgkmcnt(0)" ::: "memory");
        __builtin_amdgcn_s_barrier();
        __builtin_amdgcn_sched_barrier(0);

        // ---- S = Q @ K^T  (C layout: col=key=n*16+l15, row=l4*4+reg)
        f32x4 Sacc[4];
#pragma unroll
        for (int n = 0; n < 4; n++) Sacc[n] = (f32x4){0.f, 0.f, 0.f, 0.f};
        __builtin_amdgcn_s_setprio(1);
#pragma unroll
        for (int kq = 0; kq < 4; kq++) {
            short8 bk[4];
#pragma unroll
            for (int n = 0; n < 4; n++)
                bk[n] = *(const short8*)&Ks[(n * 16 + l15) * 128 + ((kq * 32 + l4 * 8) ^ swz)];
#pragma unroll
            for (int n = 0; n < 4; n++)
                Sacc[n] = __builtin_amdgcn_mfma_f32_16x16x32_bf16(
                    aq[kq], bk[n], Sacc[n], 0, 0, 0);
        }
        __builtin_amdgcn_s_setprio(0);

        // ---- online softmax on fragments
        bool need_mask = (t0 + 63) > (start + s0);
#pragma unroll
        for (int reg = 0; reg < 4; reg++) {
            int rloc = l4 * 4 + reg;
            int row_pos = start + s0 + rloc;
            float sv[4];
#pragma unroll
            for (int n = 0; n < 4; n++) {
                sv[n] = Sacc[n][reg];
                if (need_mask && (t0 + n * 16 + l15 > row_pos)) sv[n] = -1e30f;
            }
            float mrow = fmaxf(fmaxf(sv[0], sv[1]), fmaxf(sv[2], sv[3]));
#pragma unroll
            for (int off = 1; off < 16; off <<= 1)
                mrow = fmaxf(mrow, __shfl_xor(mrow, off));
            float m_new = fmaxf(m_run[reg], mrow);
            float alpha = __expf(m_run[reg] - m_new);
            float ps = 0.f;
#pragma unroll
            for (int n = 0; n < 4; n++) {
                sv[n] = __expf(sv[n] - m_new);
                ps += sv[n];
            }
#pragma unroll
            for (int off = 1; off < 16; off <<= 1)
                ps += __shfl_xor(ps, off);
            l_run[reg] = l_run[reg] * alpha + ps;
            m_run[reg] = m_new;
#pragma unroll
            for (int nd = 0; nd < 8; nd++) Oacc[nd][reg] *= alpha;
#pragma unroll
            for (int n = 0; n < 4; n++)
                Ps[wv][rloc * 72 + n * 16 + l15] = f2bf(sv[n]);
        }
        // (no barrier: each wave reads only its own Ps slice; lgkmcnt orders it)

        // ---- O += P @ V   (A = Ps[m=l15][k], B = Vs[n=d][k=key] swizzled)
        __builtin_amdgcn_s_setprio(1);
#pragma unroll
        for (int kp = 0; kp < 2; kp++) {
            short8 ap = *(const short8*)&Ps[wv][l15 * 72 + kp * 32 + l4 * 8];
#pragma unroll
            for (int nd = 0; nd < 8; nd++) {
                short8 bv = *(const short8*)&Vs[(nd * 16 + l15) * 64 + ((kp * 32 + l4 * 8) ^ swz)];
                Oacc[nd] = __builtin_amdgcn_mfma_f32_16x16x32_bf16(
                    ap, bv, Oacc[nd], 0, 0, 0);
            }
        }
        __builtin_amdgcn_s_setprio(0);
    }

    // ---- epilogue: O/l -> bf16 token-major
    unsigned short* ob = O + ((size_t)(b * Ssz + s0)) * HIDsz + h * Dsz;
#pragma unroll
    for (int reg = 0; reg < 4; reg++) {
        int rloc = l4 * 4 + reg;
        float inv = 1.f / l_run[reg];
#pragma unroll
        for (int nd = 0; nd < 8; nd++)
            ob[(size_t)rloc * HIDsz + nd * 16 + l15] = f2bf(Oacc[nd][reg] * inv);
    }
}

// ============================================================================
extern "C" void kernel_launch(void* const* d_in, const int* in_sizes, int n_in,
                              void* d_out, int out_size, void* d_ws, size_t ws_size,
                              hipStream_t stream) {
    (void)in_sizes; (void)n_in; (void)out_size; (void)ws_size;
    const float* hidden    = (const float*)d_in[0];
    const float* k_cache   = (const float*)d_in[1];
    const float* v_cache   = (const float*)d_in[2];
    const float* rope      = (const float*)d_in[3];
    const int*   start_idx = (const int*)d_in[5];
    const float* Wq        = (const float*)d_in[6];
    const float* Wk        = (const float*)d_in[7];
    const float* Wv        = (const float*)d_in[8];
    const float* Wo        = (const float*)d_in[9];
    const float* q_norm_w  = (const float*)d_in[10];
    const float* k_norm_w  = (const float*)d_in[11];

    float* out   = (float*)d_out;
    float* out_k = out + (size_t)Bsz * Ssz * HIDsz;
    float* out_v = out_k + (size_t)Bsz * NKVsz * CAPsz * Dsz;

    // workspace (MiB): [0,32) q_ws f32 (exactly 32 MiB), later reused as
    //                  Kbf [0,16) + Vtbf [16,32) (q_ws dead after rmsnorm-q)
    // [32,48) hidden_bf | [48,64) attn_bf | [64,80) qbf
    // [80,128) Wqkv_t (6144 x 4096 bf16 = 48 MiB); Wo_t reuses [80,112).
    char* ws = (char*)d_ws;
    float*          q_ws      = (float*)ws;
    unsigned short* Kbf       = (unsigned short*)ws;
    unsigned short* Vtbf      = (unsigned short*)(ws + (((size_t) 16) << 20));
    unsigned short* hidden_bf = (unsigned short*)(ws + (((size_t) 32) << 20));
    unsigned short* attn_bf   = (unsigned short*)(ws + (((size_t) 48) << 20));
    unsigned short* qbf       = (unsigned short*)(ws + (((size_t) 64) << 20));
    unsigned short* Wqkv_t    = (unsigned short*)(ws + (((size_t) 80) << 20));
    unsigned short* Wo_t      = Wqkv_t;   // reused after QKV-GEMM

    const size_t cache_bytes = (size_t)Bsz * NKVsz * CAPsz * Dsz * sizeof(float);
    (void)hipMemcpyAsync(out_k, k_cache, cache_bytes, hipMemcpyDeviceToDevice, stream);
    (void)hipMemcpyAsync(out_v, v_cache, cache_bytes, hipMemcpyDeviceToDevice, stream);

    // bf16 conversions / fused weight transpose (into stacked Wqkv_t)
    convert_bf16_kernel<<<8192, 256, 0, stream>>>(hidden, hidden_bf, 2048 * 4096 / 4);
    transpose_wqkv_kernel<<<dim3(96, 64), 256, 0, stream>>>(Wq, Wk, Wv, Wqkv_t);

    // Fused QKV projection (MFMA), 768 blocks
    gemm_qkv_kernel<<<dim3(48, 16), 256, 0, stream>>>(
        hidden_bf, Wqkv_t, q_ws, out_k, out_v, start_idx);

    // RMSNorm + RoPE: q -> qbf (bf16, pre-scaled); k in-place on cache slice
    // (mode 1 also writes bf16 rows straight into Kbf -- NOTE Kbf aliases
    //  q_ws, but mode-1 touches only the K-cache region out_k, and the Kbf
    //  rows it writes are in [0,16) MiB which q_ws no longer needs: q reads
    //  for rmsnorm-q run in the PREVIOUS launch. Order: rmsnorm-q first.)
    rmsnorm_rope_kernel<<<16384, 256, 0, stream>>>(q_ws, qbf, q_norm_w, rope, start_idx, NHsz, 0);
    rmsnorm_rope_kernel<<<4096, 256, 0, stream>>>(out_k, Kbf, k_norm_w, rope, start_idx, NKVsz, 1);

    // K cache prefix rows -> bf16 (rmsnorm wrote the new rows); V -> bf16
    // transposed [d][cap], skipping tiles beyond start+S
    convert_k_prefix_kernel<<<8192, 256, 0, stream>>>(out_k, Kbf, start_idx);
    transpose_v_kernel<<<dim3(32, 2, 32), 256, 0, stream>>>(out_v, Vtbf, start_idx);

    // MFMA flash attention (writes bf16 token-major), 16-row q-tiles
    attn_mfma_kernel<<<dim3(32, NKVsz, Bsz), 256, 0, stream>>>(qbf, Kbf, Vtbf, attn_bf, start_idx);

    // Wo transpose (Wqkv_t region free after QKV-proj), then output projection
    transpose_bf16_kernel<<<dim3(64, 64), 256, 0, stream>>>(Wo, Wo_t, NHsz * Dsz, HIDsz);
    gemm_bf16_kernel<<<dim3(32, 16), 256, 0, stream>>>(attn_bf, Wo_t, out, 2048, 4096, 4096);
}

// Round 5
// 662.331 us; speedup vs baseline: 1.0318x; 1.0318x over previous
//
#include <hip/hip_runtime.h>
#include <hip/hip_bf16.h>
#include <cstdint>

#define Bsz   4
#define Ssz   512
#define HIDsz 4096
#define NHsz  32
#define NKVsz 8
#define Dsz   128
#define CAPsz 2048
#define EPSf  1e-6f
#define QK_SCALEf 0.08838834764831845f  // 1/sqrt(128)

typedef __attribute__((ext_vector_type(8))) short short8;
typedef __attribute__((ext_vector_type(4))) float f32x4;

__device__ __forceinline__ unsigned short f2bf(float x) {
    unsigned u = __float_as_uint(x);
    return (unsigned short)((u + 0x7fffu + ((u >> 16) & 1u)) >> 16);
}

// async 16B global->LDS; lds base must be WAVE-UNIFORM (HW adds lane*16)
__device__ __forceinline__ void gload16(const void* g, void* l) {
    __builtin_amdgcn_global_load_lds(
        (const __attribute__((address_space(1))) unsigned int*)g,
        (__attribute__((address_space(3))) unsigned int*)l, 16, 0, 0);
}

// ============================================================================
// f32 -> bf16 flat convert (vectorized float4 -> ushort4)
// ============================================================================
__global__ __launch_bounds__(256) void convert_bf16_kernel(
    const float* __restrict__ in, unsigned short* __restrict__ out, int n4)
{
    int i = blockIdx.x * blockDim.x + threadIdx.x;
    if (i < n4) {
        float4 v = ((const float4*)in)[i];
        ushort4 o;
        o.x = f2bf(v.x); o.y = f2bf(v.y); o.z = f2bf(v.z); o.w = f2bf(v.w);
        ((ushort4*)out)[i] = o;
    }
}

// ============================================================================
// K cache f32 -> bf16, but only rows pos < start (prefix). Rows
// [start, start+S) are written bf16 by the fused QKV epilogue; rows >=
// start+S are never read by attn.
// ============================================================================
__global__ __launch_bounds__(256) void convert_k_prefix_kernel(
    const float* __restrict__ in, unsigned short* __restrict__ out,
    const int* __restrict__ start_idx)
{
    int i = blockIdx.x * blockDim.x + threadIdx.x;   // one float4 group
    int pos = (i >> 5) & (CAPsz - 1);                // 32 groups per 128-d row
    int b   = i >> 19;                               // 2^19 groups per batch
    if (pos >= start_idx[b]) return;
    float4 v = ((const float4*)in)[i];
    ushort4 o;
    o.x = f2bf(v.x); o.y = f2bf(v.y); o.z = f2bf(v.z); o.w = f2bf(v.w);
    ((ushort4*)out)[i] = o;
}

// ============================================================================
// W (K x N, f32 row-major) -> Wt (N x K, bf16 row-major). 64x64 tiles.
// (used for Wo)
// ============================================================================
__global__ __launch_bounds__(256) void transpose_bf16_kernel(
    const float* __restrict__ W, unsigned short* __restrict__ Wt, int K, int N)
{
    __shared__ float tile[64][65];
    const int k0 = blockIdx.y * 64, n0 = blockIdx.x * 64;
    const int t = threadIdx.x;
    const int tr = t >> 4, tc4 = (t & 15) * 4;
#pragma unroll
    for (int i = 0; i < 4; i++) {
        int r = tr + i * 16;
        float4 v = *(const float4*)(W + (size_t)(k0 + r) * N + n0 + tc4);
        tile[r][tc4 + 0] = v.x; tile[r][tc4 + 1] = v.y;
        tile[r][tc4 + 2] = v.z; tile[r][tc4 + 3] = v.w;
    }
    __syncthreads();
#pragma unroll
    for (int i = 0; i < 4; i++) {
        int nr = tr + i * 16;
        ushort4 o;
        o.x = f2bf(tile[tc4 + 0][nr]);
        o.y = f2bf(tile[tc4 + 1][nr]);
        o.z = f2bf(tile[tc4 + 2][nr]);
        o.w = f2bf(tile[tc4 + 3][nr]);
        *(ushort4*)(Wt + (size_t)(n0 + nr) * K + k0 + tc4) = o;
    }
}

// ============================================================================
// Fused Wq/Wk/Wv transpose into stacked Wqkv_t (6144 x 4096 bf16).
// blockIdx.x = stacked 64-col tile: [0,64) Q, [64,80) K, [80,96) V.
// ============================================================================
__global__ __launch_bounds__(256) void transpose_wqkv_kernel(
    const float* __restrict__ Wq, const float* __restrict__ Wk,
    const float* __restrict__ Wv, unsigned short* __restrict__ Wt)
{
    __shared__ float tile[64][65];
    const int nt = blockIdx.x;
    const int k0 = blockIdx.y * 64;
    const float* W; int srcN, c0;
    if (nt < 64)      { W = Wq; srcN = 4096; c0 = nt * 64; }
    else if (nt < 80) { W = Wk; srcN = 1024; c0 = (nt - 64) * 64; }
    else              { W = Wv; srcN = 1024; c0 = (nt - 80) * 64; }
    const int t = threadIdx.x;
    const int tr = t >> 4, tc4 = (t & 15) * 4;
#pragma unroll
    for (int i = 0; i < 4; i++) {
        int r = tr + i * 16;
        float4 v = *(const float4*)(W + (size_t)(k0 + r) * srcN + c0 + tc4);
        tile[r][tc4 + 0] = v.x; tile[r][tc4 + 1] = v.y;
        tile[r][tc4 + 2] = v.z; tile[r][tc4 + 3] = v.w;
    }
    __syncthreads();
    const int n0 = nt * 64;   // stacked output row base
#pragma unroll
    for (int i = 0; i < 4; i++) {
        int nr = tr + i * 16;
        ushort4 o;
        o.x = f2bf(tile[tc4 + 0][nr]);
        o.y = f2bf(tile[tc4 + 1][nr]);
        o.z = f2bf(tile[tc4 + 2][nr]);
        o.w = f2bf(tile[tc4 + 3][nr]);
        *(ushort4*)(Wt + (size_t)(n0 + nr) * HIDsz + k0 + tc4) = o;
    }
}

// ============================================================================
// V cache (B,NKV,CAP,D f32) -> Vt (B,NKV,D,CAP bf16). 64x64 tiles per (b,kv).
// Skips cap-tiles beyond start+S (attn never reads them).
// ============================================================================
__global__ __launch_bounds__(256) void transpose_v_kernel(
    const float* __restrict__ V, unsigned short* __restrict__ Vt,
    const int* __restrict__ start_idx)
{
    __shared__ float tile[64][65];   // [cap][d]
    const int c0 = blockIdx.x * 64, d0 = blockIdx.y * 64, bk = blockIdx.z;
    if (c0 >= start_idx[bk >> 3] + Ssz) return;
    const int t = threadIdx.x;
    const int tr = t >> 4, tc4 = (t & 15) * 4;
    const float* base = V + (size_t)bk * CAPsz * Dsz;
#pragma unroll
    for (int i = 0; i < 4; i++) {
        int r = tr + i * 16;
        float4 v = *(const float4*)(base + (size_t)(c0 + r) * Dsz + d0 + tc4);
        tile[r][tc4 + 0] = v.x; tile[r][tc4 + 1] = v.y;
        tile[r][tc4 + 2] = v.z; tile[r][tc4 + 3] = v.w;
    }
    __syncthreads();
    unsigned short* ob = Vt + (size_t)bk * Dsz * CAPsz;
#pragma unroll
    for (int i = 0; i < 4; i++) {
        int dr = tr + i * 16;
        ushort4 o;
        o.x = f2bf(tile[tc4 + 0][dr]);
        o.y = f2bf(tile[tc4 + 1][dr]);
        o.z = f2bf(tile[tc4 + 2][dr]);
        o.w = f2bf(tile[tc4 + 3][dr]);
        *(ushort4*)(ob + (size_t)(d0 + dr) * CAPsz + c0 + tc4) = o;
    }
}

// ============================================================================
// bf16 MFMA GEMM (m97 structure): C(MxN,f32) = A(MxK,bf16) @ Bt(NxK,bf16)^T
// Plain row-major f32 write (output projection).
// ============================================================================
__global__ __launch_bounds__(256, 3) void gemm_bf16_kernel(
    const unsigned short* __restrict__ A,   // M x K
    const unsigned short* __restrict__ Bt,  // N x K
    float* __restrict__ C, int M, int N, int K)
{
    __shared__ __align__(16) unsigned short As[128 * 64];
    __shared__ __align__(16) unsigned short Bs[128 * 64];
    const int t    = threadIdx.x;
    const int lane = t & 63, wv = t >> 6;
    const int m0 = blockIdx.y * 128, n0 = blockIdx.x * 128;
    const int rw = (wv & 1) * 64, cw = (wv >> 1) * 64;

    f32x4 acc[4][4];
#pragma unroll
    for (int r = 0; r < 4; r++)
#pragma unroll
        for (int c = 0; c < 4; c++) acc[r][c] = (f32x4){0.f, 0.f, 0.f, 0.f};

    const int arow = lane >> 3;          // 0..7 row within 8-row chunk
    const int acol = (lane & 7) * 8;     // k offset (8 bf16 = 16 B)
    const int fr = lane & 15, fq = (lane >> 4) * 8;

    for (int k0 = 0; k0 < K; k0 += 64) {
        __syncthreads();
#pragma unroll
        for (int i = 0; i < 4; i++) {
            int ro = (i * 4 + wv) * 8;   // 16 chunks x 8 rows = 128 rows
            gload16(A  + (size_t)(m0 + ro + arow) * K + k0 + acol, As + (size_t)ro * 64);
            gload16(Bt + (size_t)(n0 + ro + arow) * K + k0 + acol, Bs + (size_t)ro * 64);
        }
        __syncthreads();
#pragma unroll
        for (int kk = 0; kk < 2; kk++) {
            short8 af[4], bfr[4];
#pragma unroll
            for (int r = 0; r < 4; r++)
                af[r] = *(const short8*)&As[(rw + r * 16 + fr) * 64 + kk * 32 + fq];
#pragma unroll
            for (int c = 0; c < 4; c++)
                bfr[c] = *(const short8*)&Bs[(cw + c * 16 + fr) * 64 + kk * 32 + fq];
#pragma unroll
            for (int r = 0; r < 4; r++)
#pragma unroll
                for (int c = 0; c < 4; c++)
                    acc[r][c] = __builtin_amdgcn_mfma_f32_16x16x32_bf16(
                        af[r], bfr[c], acc[r][c], 0, 0, 0);
        }
    }

#pragma unroll
    for (int r = 0; r < 4; r++) {
#pragma unroll
        for (int c = 0; c < 4; c++) {
            int col = n0 + cw + c * 16 + (lane & 15);
#pragma unroll
            for (int reg = 0; reg < 4; reg++) {
                int row = m0 + rw + r * 16 + (lane >> 4) * 4 + reg;
                C[(size_t)row * N + col] = acc[r][c][reg];
            }
        }
    }
}

// ============================================================================
// R5: FUSED QKV projection GEMM + RMSNorm + RoPE epilogue.
// Bt = [Wq_t; Wk_t; Wv_t] stacked, N = 6144. Each Q/K block's 128 n-cols are
// exactly one head's 128 d's, so rmsnorm's row-sum is block-local:
//   - per-row x^2 partials reduced over l15 (shfl) + the 2 cw-waves (ssbuf)
//   - RoPE partner (d^64) lives in wave wv^2 -> exchange via xbuf (stride 17
//     pads away bank conflicts), one r-group at a time
//   - d<64 vs d>=64 is wave-uniform (cw)
// Q blocks write pre-scaled bf16 qbf directly. K blocks write post-norm+rope
// f32 cache AND bf16 Kbf. V blocks: plain f32 scatter (no norm).
// ============================================================================
__global__ __launch_bounds__(256, 3) void gemm_qkv_kernel(
    const unsigned short* __restrict__ A,    // 2048 x 4096 bf16
    const unsigned short* __restrict__ Bt,   // 6144 x 4096 bf16
    unsigned short* __restrict__ Qout,       // qbf 2048 x 4096 bf16 (pre-scaled)
    float* __restrict__ Ck,                  // [B][NKV][CAP][D] f32
    float* __restrict__ Cv,                  // [B][NKV][CAP][D] f32
    unsigned short* __restrict__ Kbf,        // [B][NKV][CAP][D] bf16
    const float* __restrict__ rope,          // [MAXPOS][128] cos|sin
    const float* __restrict__ qw,            // q_norm_w [128]
    const float* __restrict__ knw,           // k_norm_w [128]
    const int* __restrict__ start_idx)
{
    __shared__ __align__(16) unsigned short As[128 * 64];
    __shared__ __align__(16) unsigned short Bs[128 * 64];
    __shared__ float ssbuf[256];         // [srow][cw-half]
    __shared__ float xbuf[256 * 17];     // exchange tile, stride 17 (bank-safe)
    const int t    = threadIdx.x;
    const int lane = t & 63, wv = t >> 6;
    const int m0 = blockIdx.y * 128, n0 = blockIdx.x * 128;
    const int rw = (wv & 1) * 64, cw = (wv >> 1) * 64;
    const int l15 = lane & 15, l4 = lane >> 4;

    f32x4 acc[4][4];
#pragma unroll
    for (int r = 0; r < 4; r++)
#pragma unroll
        for (int c = 0; c < 4; c++) acc[r][c] = (f32x4){0.f, 0.f, 0.f, 0.f};

    const int arow = lane >> 3;
    const int acol = (lane & 7) * 8;
    const int fr = l15, fq = l4 * 8;

    for (int k0 = 0; k0 < HIDsz; k0 += 64) {
        __syncthreads();
#pragma unroll
        for (int i = 0; i < 4; i++) {
            int ro = (i * 4 + wv) * 8;
            gload16(A  + (size_t)(m0 + ro + arow) * HIDsz + k0 + acol, As + (size_t)ro * 64);
            gload16(Bt + (size_t)(n0 + ro + arow) * HIDsz + k0 + acol, Bs + (size_t)ro * 64);
        }
        __syncthreads();
#pragma unroll
        for (int kk = 0; kk < 2; kk++) {
            short8 af[4], bfr[4];
#pragma unroll
            for (int r = 0; r < 4; r++)
                af[r] = *(const short8*)&As[(rw + r * 16 + fr) * 64 + kk * 32 + fq];
#pragma unroll
            for (int c = 0; c < 4; c++)
                bfr[c] = *(const short8*)&Bs[(cw + c * 16 + fr) * 64 + kk * 32 + fq];
#pragma unroll
            for (int r = 0; r < 4; r++)
#pragma unroll
                for (int c = 0; c < 4; c++)
                    acc[r][c] = __builtin_amdgcn_mfma_f32_16x16x32_bf16(
                        af[r], bfr[c], acc[r][c], 0, 0, 0);
        }
    }

    const int m0b  = m0 & (Ssz - 1);
    const int bat  = m0 >> 9;
    const int pos0 = start_idx[bat];

    // ---- V region: plain f32 cache scatter ----
    if (n0 >= 5120) {
#pragma unroll
        for (int r = 0; r < 4; r++) {
#pragma unroll
            for (int c = 0; c < 4; c++) {
                int cc = (n0 - 5120) + cw + c * 16 + l15;   // 0..1023
                int kvh = cc >> 7, d = cc & 127;
#pragma unroll
                for (int reg = 0; reg < 4; reg++) {
                    int srow = rw + r * 16 + l4 * 4 + reg;
                    int pos = pos0 + m0b + srow;
                    Cv[((size_t)(bat * NKVsz + kvh) * CAPsz + pos) * Dsz + d] = acc[r][c][reg];
                }
            }
        }
        return;
    }

    // ---- Q / K region: fused RMSNorm + RoPE ----
    const bool isQ = (n0 < 4096);
    const float* w = isQ ? qw : knw;

    // row sums of x^2 (over this block's 128 d-cols)
#pragma unroll
    for (int r = 0; r < 4; r++)
#pragma unroll
        for (int reg = 0; reg < 4; reg++) {
            float p = acc[r][0][reg] * acc[r][0][reg]
                    + acc[r][1][reg] * acc[r][1][reg]
                    + acc[r][2][reg] * acc[r][2][reg]
                    + acc[r][3][reg] * acc[r][3][reg];
#pragma unroll
            for (int off = 1; off < 16; off <<= 1) p += __shfl_xor(p, off);
            if (l15 == 0)
                ssbuf[(rw + r * 16 + l4 * 4 + reg) * 2 + (cw >> 6)] = p;
        }
    __syncthreads();

    float wv4[4];
#pragma unroll
    for (int c = 0; c < 4; c++) wv4[c] = w[cw + c * 16 + l15];

    float rn[4][4];
#pragma unroll
    for (int r = 0; r < 4; r++)
#pragma unroll
        for (int reg = 0; reg < 4; reg++) {
            int srow = rw + r * 16 + l4 * 4 + reg;
            rn[r][reg] = rsqrtf((ssbuf[srow * 2] + ssbuf[srow * 2 + 1]) * (1.f / 128.f) + EPSf);
        }

    const int kvh = isQ ? 0 : ((n0 - 4096) >> 7);

#pragma unroll
    for (int r = 0; r < 4; r++) {
        float xn[4][4];
#pragma unroll
        for (int c = 0; c < 4; c++)
#pragma unroll
            for (int reg = 0; reg < 4; reg++) {
                xn[c][reg] = acc[r][c][reg] * rn[r][reg] * wv4[c];
                xbuf[t * 17 + c * 4 + reg] = xn[c][reg];
            }
        __syncthreads();
        float xp[4][4];
#pragma unroll
        for (int c = 0; c < 4; c++)
#pragma unroll
            for (int reg = 0; reg < 4; reg++)
                xp[c][reg] = xbuf[(t ^ 128) * 17 + c * 4 + reg];

#pragma unroll
        for (int reg = 0; reg < 4; reg++) {
            int srow = rw + r * 16 + l4 * 4 + reg;
            int pos = pos0 + m0b + srow;
            const float* rb = rope + (size_t)pos * Dsz;
#pragma unroll
            for (int c = 0; c < 4; c++) {
                int dh = cw + c * 16 + l15;
                int j = dh & 63;
                float co = rb[j], si = rb[64 + j];
                // cw==0 wave: dh<64 (x1 slot): o = x1*c - x2*s  (xp = x2)
                // cw==64 wave: dh>=64 (x2 slot): o = x2*c + x1*s (xp = x1)
                float o = (cw == 0) ? xn[c][reg] * co - xp[c][reg] * si
                                    : xn[c][reg] * co + xp[c][reg] * si;
                if (isQ) {
                    Qout[(size_t)(m0 + srow) * 4096 + n0 + dh] = f2bf(o * QK_SCALEf);
                } else {
                    size_t off = ((size_t)(bat * NKVsz + kvh) * CAPsz + pos) * Dsz + dh;
                    Ck[off]  = o;
                    Kbf[off] = f2bf(o);
                }
            }
        }
        __syncthreads();
    }
}

// ============================================================================
// MFMA flash attention (R3-proven structure). Block = (32 q-rows, kv-group,
// batch), 4 waves = 4 GQA heads sharing one K/V LDS tile. K tile [key][d],
// V^T tile [d][key], both XOR-swizzled (R1). T14 async-STAGE (R2):
// global->reg->LDS, prefetch over compute, raw s_barrier w/o vmcnt drain.
// T5 setprio around MFMA clusters.
// ============================================================================
__global__ __launch_bounds__(256, 2) void attn_mfma_kernel(
    const unsigned short* __restrict__ Qbf,   // [B][S][NH*D]
    const unsigned short* __restrict__ Kbf,   // [B][NKV][CAP][D]
    const unsigned short* __restrict__ Vtbf,  // [B][NKV][D][CAP]
    unsigned short* __restrict__ O,           // [B][S][NH*D]
    const int* __restrict__ start_idx)
{
    __shared__ __align__(16) unsigned short Ks[64 * 128];     // [key][d] swizzled
    __shared__ __align__(16) unsigned short Vs[128 * 64];     // [d][key] swizzled
    __shared__ __align__(16) unsigned short Ps[4][32 * 72];   // per-wave [row][key], pad 72

    const int t = threadIdx.x, lane = t & 63, wv = t >> 6;
    const int l15 = lane & 15, l4 = lane >> 4;
    const int qt = blockIdx.x, kv = blockIdx.y, b = blockIdx.z;
    const int h = kv * 4 + wv;
    const int s0 = qt * 32;
    const int start = start_idx[b];

    // read-side swizzle term: row&7 == l15&7 for all fragment reads
    const int swz = (l15 & 7) << 3;

    // Q a-frags: A[m=l15][k=l4*8+j], 2 m-tiles x 4 k-tiles (d=128)
    short8 aq[2][4];
    const unsigned short* qb = Qbf + ((size_t)(b * Ssz + s0)) * HIDsz + h * Dsz;
#pragma unroll
    for (int m2 = 0; m2 < 2; m2++)
#pragma unroll
        for (int kq = 0; kq < 4; kq++)
            aq[m2][kq] = *(const short8*)(qb + (size_t)(m2 * 16 + l15) * HIDsz + kq * 32 + l4 * 8);

    f32x4 Oacc[2][8];
    float m_run[2][4], l_run[2][4];
#pragma unroll
    for (int m2 = 0; m2 < 2; m2++) {
#pragma unroll
        for (int nd = 0; nd < 8; nd++) Oacc[m2][nd] = (f32x4){0.f, 0.f, 0.f, 0.f};
#pragma unroll
        for (int r = 0; r < 4; r++) { m_run[m2][r] = -1e30f; l_run[m2][r] = 0.f; }
    }

    const unsigned short* kb = Kbf + (size_t)(b * NKVsz + kv) * CAPsz * Dsz;
    const unsigned short* vb = Vtbf + (size_t)(b * NKVsz + kv) * (size_t)Dsz * CAPsz;

    int t_hi = start + s0 + 31;
    if (t_hi > CAPsz - 1) t_hi = CAPsz - 1;

    // staging geometry: K chunk i covers rows (i*4+wv)*4 + l4, 16B slot l15;
    //                   V chunk i covers rows (i*4+wv)*8 + (lane>>3), slot lane&7.
    // LDS write address carries the XOR swizzle; global reads stay linear.
    int krow[4], vrow[4];
    unsigned short* kw[4];
    unsigned short* vw[4];
#pragma unroll
    for (int i = 0; i < 4; i++) {
        int kr = (i * 4 + wv) * 4 + l4;
        krow[i] = kr;
        kw[i] = &Ks[kr * 128 + ((l15 * 8) ^ ((kr & 7) << 3))];
        int vr = (i * 4 + wv) * 8 + (lane >> 3);
        vrow[i] = vr;
        vw[i] = &Vs[vr * 64 + (((lane & 7) * 8) ^ ((vr & 7) << 3))];
    }

    // prologue: tile 0 -> regs
    short8 kreg[4], vreg[4];
#pragma unroll
    for (int i = 0; i < 4; i++) {
        kreg[i] = *(const short8*)(kb + (size_t)krow[i] * Dsz + l15 * 8);
        vreg[i] = *(const short8*)(vb + (size_t)vrow[i] * CAPsz + (lane & 7) * 8);
    }

    for (int t0 = 0; t0 <= t_hi; t0 += 64) {
        // barrier 1: all waves done reading Ks/Vs of previous tile
        asm volatile("s_waitcnt lgkmcnt(0)" ::: "memory");
        __builtin_amdgcn_s_barrier();
        __builtin_amdgcn_sched_barrier(0);

        // write tile t (regs -> LDS, swizzled)
#pragma unroll
        for (int i = 0; i < 4; i++) *(short8*)kw[i] = kreg[i];
#pragma unroll
        for (int i = 0; i < 4; i++) *(short8*)vw[i] = vreg[i];

        // issue tile t+1 global loads (land during compute; no vmcnt at barrier)
        if (t0 + 64 <= t_hi) {
            int tn = t0 + 64;
#pragma unroll
            for (int i = 0; i < 4; i++) {
                kreg[i] = *(const short8*)(kb + (size_t)(tn + krow[i]) * Dsz + l15 * 8);
                vreg[i] = *(const short8*)(vb + (size_t)vrow[i] * CAPsz + tn + (lane & 7) * 8);
            }
        }

        // barrier 2: LDS writes visible to all waves (lgkmcnt only, NOT vmcnt)
        asm volatile("s_waitcnt lgkmcnt(0)" ::: "memory");
        __builtin_amdgcn_s_barrier();
        __builtin_amdgcn_sched_barrier(0);

        // ---- S = Q @ K^T  (C layout: col=key=n*16+l15, row=m2*16+l4*4+reg)
        f32x4 Sacc[2][4];
#pragma unroll
        for (int m2 = 0; m2 < 2; m2++)
#pragma unroll
            for (int n = 0; n < 4; n++) Sacc[m2][n] = (f32x4){0.f, 0.f, 0.f, 0.f};
        __builtin_amdgcn_s_setprio(1);
#pragma unroll
        for (int kq = 0; kq < 4; kq++) {
            short8 bk[4];
#pragma unroll
            for (int n = 0; n < 4; n++)
                bk[n] = *(const short8*)&Ks[(n * 16 + l15) * 128 + ((kq * 32 + l4 * 8) ^ swz)];
#pragma unroll
            for (int m2 = 0; m2 < 2; m2++)
#pragma unroll
                for (int n = 0; n < 4; n++)
                    Sacc[m2][n] = __builtin_amdgcn_mfma_f32_16x16x32_bf16(
                        aq[m2][kq], bk[n], Sacc[m2][n], 0, 0, 0);
        }
        __builtin_amdgcn_s_setprio(0);

        // ---- online softmax on fragments
        bool need_mask = (t0 + 63) > (start + s0);
#pragma unroll
        for (int m2 = 0; m2 < 2; m2++) {
#pragma unroll
            for (int reg = 0; reg < 4; reg++) {
                int rloc = m2 * 16 + l4 * 4 + reg;
                int row_pos = start + s0 + rloc;
                float sv[4];
#pragma unroll
                for (int n = 0; n < 4; n++) {
                    sv[n] = Sacc[m2][n][reg];
                    if (need_mask && (t0 + n * 16 + l15 > row_pos)) sv[n] = -1e30f;
                }
                float mrow = fmaxf(fmaxf(sv[0], sv[1]), fmaxf(sv[2], sv[3]));
#pragma unroll
                for (int off = 1; off < 16; off <<= 1)
                    mrow = fmaxf(mrow, __shfl_xor(mrow, off));
                float m_new = fmaxf(m_run[m2][reg], mrow);
                float alpha = __expf(m_run[m2][reg] - m_new);
                float ps = 0.f;
#pragma unroll
                for (int n = 0; n < 4; n++) {
                    sv[n] = __expf(sv[n] - m_new);
                    ps += sv[n];
                }
#pragma unroll
                for (int off = 1; off < 16; off <<= 1)
                    ps += __shfl_xor(ps, off);
                l_run[m2][reg] = l_run[m2][reg] * alpha + ps;
                m_run[m2][reg] = m_new;
#pragma unroll
                for (int nd = 0; nd < 8; nd++) Oacc[m2][nd][reg] *= alpha;
#pragma unroll
                for (int n = 0; n < 4; n++)
                    Ps[wv][rloc * 72 + n * 16 + l15] = f2bf(sv[n]);
            }
        }
        // (no barrier: each wave reads only its own Ps slice; lgkmcnt orders it)

        // ---- O += P @ V   (A = Ps[m=l15][k], B = Vs[n=d][k=key] swizzled)
        __builtin_amdgcn_s_setprio(1);
#pragma unroll
        for (int kp = 0; kp < 2; kp++) {
            short8 ap[2];
#pragma unroll
            for (int m2 = 0; m2 < 2; m2++)
                ap[m2] = *(const short8*)&Ps[wv][(m2 * 16 + l15) * 72 + kp * 32 + l4 * 8];
#pragma unroll
            for (int nd = 0; nd < 8; nd++) {
                short8 bv = *(const short8*)&Vs[(nd * 16 + l15) * 64 + ((kp * 32 + l4 * 8) ^ swz)];
#pragma unroll
                for (int m2 = 0; m2 < 2; m2++)
                    Oacc[m2][nd] = __builtin_amdgcn_mfma_f32_16x16x32_bf16(
                        ap[m2], bv, Oacc[m2][nd], 0, 0, 0);
            }
        }
        __builtin_amdgcn_s_setprio(0);
    }

    // ---- epilogue: O/l -> bf16 token-major
    unsigned short* ob = O + ((size_t)(b * Ssz + s0)) * HIDsz + h * Dsz;
#pragma unroll
    for (int m2 = 0; m2 < 2; m2++)
#pragma unroll
        for (int reg = 0; reg < 4; reg++) {
            int rloc = m2 * 16 + l4 * 4 + reg;
            float inv = 1.f / l_run[m2][reg];
#pragma unroll
            for (int nd = 0; nd < 8; nd++)
                ob[(size_t)rloc * HIDsz + nd * 16 + l15] = f2bf(Oacc[m2][nd][reg] * inv);
        }
}

// ============================================================================
extern "C" void kernel_launch(void* const* d_in, const int* in_sizes, int n_in,
                              void* d_out, int out_size, void* d_ws, size_t ws_size,
                              hipStream_t stream) {
    (void)in_sizes; (void)n_in; (void)out_size; (void)ws_size;
    const float* hidden    = (const float*)d_in[0];
    const float* k_cache   = (const float*)d_in[1];
    const float* v_cache   = (const float*)d_in[2];
    const float* rope      = (const float*)d_in[3];
    const int*   start_idx = (const int*)d_in[5];
    const float* Wq        = (const float*)d_in[6];
    const float* Wk        = (const float*)d_in[7];
    const float* Wv        = (const float*)d_in[8];
    const float* Wo        = (const float*)d_in[9];
    const float* q_norm_w  = (const float*)d_in[10];
    const float* k_norm_w  = (const float*)d_in[11];

    float* out   = (float*)d_out;
    float* out_k = out + (size_t)Bsz * Ssz * HIDsz;
    float* out_v = out_k + (size_t)Bsz * NKVsz * CAPsz * Dsz;

    // workspace (MiB): [0,16) Kbf | [16,32) Vtbf | [32,48) hidden_bf
    // [48,64) attn_bf | [64,80) qbf | [80,128) Wqkv_t (6144x4096 bf16 = 48);
    // Wo_t reuses [80,112) after QKV-GEMM.
    char* ws = (char*)d_ws;
    unsigned short* Kbf       = (unsigned short*)ws;
    unsigned short* Vtbf      = (unsigned short*)(ws + (((size_t) 16) << 20));
    unsigned short* hidden_bf = (unsigned short*)(ws + (((size_t) 32) << 20));
    unsigned short* attn_bf   = (unsigned short*)(ws + (((size_t) 48) << 20));
    unsigned short* qbf       = (unsigned short*)(ws + (((size_t) 64) << 20));
    unsigned short* Wqkv_t    = (unsigned short*)(ws + (((size_t) 80) << 20));
    unsigned short* Wo_t      = Wqkv_t;   // reused after QKV-GEMM

    const size_t cache_bytes = (size_t)Bsz * NKVsz * CAPsz * Dsz * sizeof(float);
    (void)hipMemcpyAsync(out_k, k_cache, cache_bytes, hipMemcpyDeviceToDevice, stream);
    (void)hipMemcpyAsync(out_v, v_cache, cache_bytes, hipMemcpyDeviceToDevice, stream);

    // bf16 conversions / fused weight transpose (into stacked Wqkv_t)
    convert_bf16_kernel<<<8192, 256, 0, stream>>>(hidden, hidden_bf, 2048 * 4096 / 4);
    transpose_wqkv_kernel<<<dim3(96, 64), 256, 0, stream>>>(Wq, Wk, Wv, Wqkv_t);

    // Fused QKV projection + RMSNorm + RoPE (MFMA), 768 blocks
    gemm_qkv_kernel<<<dim3(48, 16), 256, 0, stream>>>(
        hidden_bf, Wqkv_t, qbf, out_k, out_v, Kbf, rope,
        q_norm_w, k_norm_w, start_idx);

    // K cache prefix rows -> bf16; V -> bf16 transposed [d][cap] (<= start+S)
    convert_k_prefix_kernel<<<8192, 256, 0, stream>>>(out_k, Kbf, start_idx);
    transpose_v_kernel<<<dim3(32, 2, 32), 256, 0, stream>>>(out_v, Vtbf, start_idx);

    // MFMA flash attention (writes bf16 token-major), 32-row q-tiles
    attn_mfma_kernel<<<dim3(16, NKVsz, Bsz), 256, 0, stream>>>(qbf, Kbf, Vtbf, attn_bf, start_idx);

    // Wo transpose (Wqkv_t region free after QKV-proj), then output projection
    transpose_bf16_kernel<<<dim3(64, 64), 256, 0, stream>>>(Wo, Wo_t, NHsz * Dsz, HIDsz);
    gemm_bf16_kernel<<<dim3(32, 16), 256, 0, stream>>>(attn_bf, Wo_t, out, 2048, 4096, 4096);
}